// Round 1
// baseline (1450.772 us; speedup 1.0000x reference)
//
#include <hip/hip_runtime.h>
#include <stdint.h>

// Shapes
#define VOCAB 32000
#define EMBED 256
#define H1DIM 512
#define KVDIM 128
#define BB    32
#define SS    512
#define TT    256
#define MTOT  (BB*TT)   // 8192

typedef __attribute__((ext_vector_type(8))) short  short8;
typedef __attribute__((ext_vector_type(4))) float  floatx4;

__device__ __forceinline__ unsigned short f2bf(float f){
  unsigned int x = __float_as_uint(f);
  x += 0x7fffu + ((x >> 16) & 1u);          // round-nearest-even to bf16
  return (unsigned short)(x >> 16);
}
__device__ __forceinline__ float sigm(float x){ return 1.0f/(1.0f + __expf(-x)); }

__device__ __forceinline__ void async_lds16(const void* g, void* s){
  typedef const __attribute__((address_space(1))) unsigned int* gp_t;
  typedef __attribute__((address_space(3))) unsigned int* lp_t;
  __builtin_amdgcn_global_load_lds((gp_t)g, (lp_t)s, 16, 0, 0);
}

// ---------------- kernel: E f32 -> bf16 ----------------
__global__ __launch_bounds__(256) void cvt_kernel(const float* __restrict__ src,
                                                  unsigned short* __restrict__ dst, int n4){
  int i = blockIdx.x*256 + threadIdx.x;
  if (i >= n4) return;
  float4 v = ((const float4*)src)[i];
  ushort4 o;
  o.x = f2bf(v.x); o.y = f2bf(v.y); o.z = f2bf(v.z); o.w = f2bf(v.w);
  ((ushort4*)dst)[i] = o;
}

// ---------------- LSTM-cell GEMM (f32 vector), fused i/g/o + activation ----------------
// C[m][j] over 64x64 tile; A row stride == K; W row stride == K.
// h = sigmoid(o) * tanh( sigmoid(i) * tanh(g) )
template<bool GATHER, int K, int RI, int RG, int RO, int OSTRIDE>
__global__ __launch_bounds__(256) void lstm_gemm_kernel(
    const float* __restrict__ A, const int* __restrict__ y,
    const float* __restrict__ W, const float* __restrict__ b_ih,
    const float* __restrict__ b_hh, float* __restrict__ Hout)
{
  // transposed LDS tiles: [k][row], stride 68 floats (16B aligned rows, bank offset 4)
  __shared__ __align__(16) float At[32][68];
  __shared__ __align__(16) float Bi[32][68];
  __shared__ __align__(16) float Bg[32][68];
  __shared__ __align__(16) float Bo[32][68];

  const int tid = threadIdx.x;
  const int j0  = blockIdx.x * 64;
  const int m0  = blockIdx.y * 64;

  const int sr  = tid >> 3;   // 0..31 staging row
  const int skc = tid & 7;    // k-chunk (4 floats)

  const float* arow[2];
  if (GATHER){
    #pragma unroll
    for (int q=0;q<2;q++){
      int m = m0 + sr + q*32;
      int t = m & (TT-1), bb = m >> 8;
      int tok = (t == 0) ? 0 : y[bb*TT + t - 1];
      arow[q] = A + (size_t)tok * K;
    }
  } else {
    arow[0] = A + (size_t)(m0 + sr) * K;
    arow[1] = A + (size_t)(m0 + sr + 32) * K;
  }
  const float* wrow[6];
  wrow[0] = W + (size_t)(RI + j0 + sr) * K;
  wrow[1] = W + (size_t)(RI + j0 + sr + 32) * K;
  wrow[2] = W + (size_t)(RG + j0 + sr) * K;
  wrow[3] = W + (size_t)(RG + j0 + sr + 32) * K;
  wrow[4] = W + (size_t)(RO + j0 + sr) * K;
  wrow[5] = W + (size_t)(RO + j0 + sr + 32) * K;

  float aI[4][4] = {{0}}, aG[4][4] = {{0}}, aO[4][4] = {{0}};
  const int tx = tid & 15, ty = tid >> 4;

  for (int k0 = 0; k0 < K; k0 += 32){
    __syncthreads();   // protect LDS reuse
    #pragma unroll
    for (int q=0;q<2;q++){
      int r = sr + q*32;
      float4 va = *(const float4*)(arow[q]   + k0 + skc*4);
      float4 vi = *(const float4*)(wrow[q]   + k0 + skc*4);
      float4 vg = *(const float4*)(wrow[2+q] + k0 + skc*4);
      float4 vo = *(const float4*)(wrow[4+q] + k0 + skc*4);
      At[skc*4+0][r]=va.x; At[skc*4+1][r]=va.y; At[skc*4+2][r]=va.z; At[skc*4+3][r]=va.w;
      Bi[skc*4+0][r]=vi.x; Bi[skc*4+1][r]=vi.y; Bi[skc*4+2][r]=vi.z; Bi[skc*4+3][r]=vi.w;
      Bg[skc*4+0][r]=vg.x; Bg[skc*4+1][r]=vg.y; Bg[skc*4+2][r]=vg.z; Bg[skc*4+3][r]=vg.w;
      Bo[skc*4+0][r]=vo.x; Bo[skc*4+1][r]=vo.y; Bo[skc*4+2][r]=vo.z; Bo[skc*4+3][r]=vo.w;
    }
    __syncthreads();
    #pragma unroll 8
    for (int kk=0;kk<32;kk++){
      float a[4], bi[4], bg[4], bo[4];
      *(float4*)a  = *(const float4*)&At[kk][ty*4];
      *(float4*)bi = *(const float4*)&Bi[kk][tx*4];
      *(float4*)bg = *(const float4*)&Bg[kk][tx*4];
      *(float4*)bo = *(const float4*)&Bo[kk][tx*4];
      #pragma unroll
      for (int mi=0;mi<4;mi++){
        #pragma unroll
        for (int ni=0;ni<4;ni++){
          aI[mi][ni] = fmaf(a[mi], bi[ni], aI[mi][ni]);
          aG[mi][ni] = fmaf(a[mi], bg[ni], aG[mi][ni]);
          aO[mi][ni] = fmaf(a[mi], bo[ni], aO[mi][ni]);
        }
      }
    }
  }
  #pragma unroll
  for (int ni=0;ni<4;ni++){
    int j = j0 + tx*4 + ni;
    float bI = b_ih[RI+j] + b_hh[RI+j];
    float bG = b_ih[RG+j] + b_hh[RG+j];
    float bO = b_ih[RO+j] + b_hh[RO+j];
    #pragma unroll
    for (int mi=0;mi<4;mi++){
      float iv = sigm(aI[mi][ni] + bI);
      float gv = tanhf(aG[mi][ni] + bG);
      float ov = sigm(aO[mi][ni] + bO);
      Hout[(size_t)(m0 + ty*4 + mi) * OSTRIDE + j] = ov * tanhf(iv * gv);
    }
  }
}

// ---------------- attention: energy -> masked softmax -> context; emits out_ctx bf16 ----------------
// block = (b, 16-token t-tile); 512 blocks x 256 threads
__global__ __launch_bounds__(256) void attn_kernel(
    const float* __restrict__ key, const float* __restrict__ value,
    const int* __restrict__ enc_len, const float* __restrict__ h2,
    unsigned short* __restrict__ oc)
{
  __shared__ __align__(16) float h2s[16][128];   // 8 KB
  __shared__ __align__(16) float kst[128][36];   // key chunk transposed [c][s_local], 18 KB
  __shared__ __align__(16) float es[16][512];    // 32 KB
  __shared__ float red[16][17];
  __shared__ float rmax[16], rsinv[16];

  const int tid = threadIdx.x;
  const int b   = blockIdx.x >> 4;
  const int t0  = (blockIdx.x & 15) * 16;
  const int L   = enc_len[b];

  { // load h2 tile + emit left half of out_ctx (bf16)
    int r = tid >> 4, c0 = (tid & 15) * 8;
    const float* src = h2 + ((size_t)(b*TT + t0 + r))*KVDIM + c0;
    float4 v0 = *(const float4*)src;
    float4 v1 = *(const float4*)(src + 4);
    *(float4*)&h2s[r][c0]   = v0;
    *(float4*)&h2s[r][c0+4] = v1;
    unsigned short* od = oc + ((size_t)(b*TT + t0 + r))*EMBED + c0;
    od[0]=f2bf(v0.x); od[1]=f2bf(v0.y); od[2]=f2bf(v0.z); od[3]=f2bf(v0.w);
    od[4]=f2bf(v1.x); od[5]=f2bf(v1.y); od[6]=f2bf(v1.z); od[7]=f2bf(v1.w);
  }

  const int ksr = tid >> 3, kcg = tid & 7;    // staging: 32 rows x 8 col-groups
  const int sl  = tid & 31, g = tid >> 5;     // energy: 32 s x 8 groups (2 tt each)
  const int tb  = g*2;

  for (int s0 = 0; s0 < SS; s0 += 32){
    __syncthreads();
    { // stage key[s0..s0+31][:] transposed
      const float* kr = key + ((size_t)(b*SS + s0 + ksr))*KVDIM;
      #pragma unroll
      for (int u=0; u<4; u++){
        int c = u*32 + kcg*4;
        float4 kv = *(const float4*)(kr + c);
        kst[c+0][ksr]=kv.x; kst[c+1][ksr]=kv.y; kst[c+2][ksr]=kv.z; kst[c+3][ksr]=kv.w;
      }
    }
    __syncthreads();
    float a0=0.f, a1=0.f;
    #pragma unroll 4
    for (int c=0;c<128;c+=4){
      float k0v=kst[c][sl], k1v=kst[c+1][sl], k2v=kst[c+2][sl], k3v=kst[c+3][sl];
      float4 h0 = *(const float4*)&h2s[tb][c];
      float4 h1 = *(const float4*)&h2s[tb+1][c];
      a0 = fmaf(k0v,h0.x, fmaf(k1v,h0.y, fmaf(k2v,h0.z, fmaf(k3v,h0.w, a0))));
      a1 = fmaf(k0v,h1.x, fmaf(k1v,h1.y, fmaf(k2v,h1.z, fmaf(k3v,h1.w, a1))));
    }
    int s = s0 + sl;
    bool valid = s < L;
    es[tb  ][s] = valid ? a0 : -1e9f;
    es[tb+1][s] = valid ? a1 : -1e9f;
  }
  __syncthreads();

  { // masked softmax per row (16 threads/row)
    int row = tid >> 4, l = tid & 15;
    float mx = -3e38f;
    for (int s=l; s<SS; s+=16) mx = fmaxf(mx, es[row][s]);
    red[row][l] = mx;
    __syncthreads();
    if (l == 0){
      float m2 = -3e38f;
      #pragma unroll
      for (int i=0;i<16;i++) m2 = fmaxf(m2, red[row][i]);
      rmax[row] = m2;
    }
    __syncthreads();
    float m = rmax[row], sum = 0.f;
    for (int s=l; s<SS; s+=16){
      float p = __expf(es[row][s] - m);   // masked -> exp(-1e9-m) == 0
      es[row][s] = p;
      sum += p;
    }
    red[row][l] = sum;
    __syncthreads();
    if (l == 0){
      float tsum = 0.f;
      #pragma unroll
      for (int i=0;i<16;i++) tsum += red[row][i];
      rsinv[row] = 1.0f / tsum;
    }
    __syncthreads();
  }

  { // context = P @ value, emit right half of out_ctx (bf16)
    int v = tid & 127, hh = tid >> 7;
    float acc[8] = {0,0,0,0,0,0,0,0};
    const float* vp = value + ((size_t)b*SS)*KVDIM + v;
    #pragma unroll 2
    for (int s=0; s<SS; s+=4){
      float x0 = vp[(size_t)(s+0)*KVDIM];
      float x1 = vp[(size_t)(s+1)*KVDIM];
      float x2 = vp[(size_t)(s+2)*KVDIM];
      float x3 = vp[(size_t)(s+3)*KVDIM];
      #pragma unroll
      for (int i=0;i<8;i++){
        float4 e = *(const float4*)&es[hh*8+i][s];
        acc[i] = fmaf(e.x,x0, fmaf(e.y,x1, fmaf(e.z,x2, fmaf(e.w,x3, acc[i]))));
      }
    }
    #pragma unroll
    for (int i=0;i<8;i++){
      int tt = hh*8 + i;
      oc[((size_t)(b*TT + t0 + tt))*EMBED + KVDIM + v] = f2bf(acc[i] * rsinv[tt]);
    }
  }
}

// ---------------- final GEMM: out[b][v][t] = [h2,ctx](b,t,:) . E[v,:] + b_out[v] ----------------
// bf16 MFMA 16x16x32, 128x128 tile, 4 waves of 64x64, global_load_lds staging (m97 structure)
__global__ __launch_bounds__(256) void out_gemm_kernel(
    const unsigned short* __restrict__ Ebf, const unsigned short* __restrict__ OC,
    const float* __restrict__ b_out, float* __restrict__ out)
{
  __shared__ __align__(16) char smem[16384];
  char* As = smem;          // E tile: 128 rows(v) x 32 bf16 (64B rows)
  char* Bs = smem + 8192;   // out_ctx tile: 128 rows(t) x 32 bf16

  const int tid  = threadIdx.x;
  const int lane = tid & 63, w = tid >> 6;
  const int v0 = blockIdx.x * 128;
  const int t0 = blockIdx.y * 128;
  const int b  = blockIdx.z;
  const int wv = (w & 1) * 64, wt = (w >> 1) * 64;

  const char* Ab = (const char*)Ebf + (size_t)v0 * (EMBED*2);
  const char* Bb = (const char*)OC  + ((size_t)(b*TT + t0)) * (EMBED*2);

  const int r0 = tid >> 2;            // staging row (q=0); q=1 adds 64
  const int cb = (tid & 3) * 16;      // byte offset within 64B row chunk
  char* ldsA0 = As        + w * 1024; // wave-uniform base; HW adds lane*16
  char* ldsA1 = As + 4096 + w * 1024;
  char* ldsB0 = Bs        + w * 1024;
  char* ldsB1 = Bs + 4096 + w * 1024;

  floatx4 zero = {0.f, 0.f, 0.f, 0.f};
  floatx4 acc[4][4];
  #pragma unroll
  for (int i=0;i<4;i++)
    #pragma unroll
    for (int j=0;j<4;j++) acc[i][j] = zero;

  const int fr = lane & 15;           // row within 16
  const int fo = (lane >> 4) * 16;    // k-fragment byte offset (8 bf16)

  for (int kt = 0; kt < 8; kt++){
    const size_t ko = (size_t)kt * 64;
    async_lds16(Ab + (size_t)(r0     )*512 + ko + cb, ldsA0);
    async_lds16(Ab + (size_t)(r0 + 64)*512 + ko + cb, ldsA1);
    async_lds16(Bb + (size_t)(r0     )*512 + ko + cb, ldsB0);
    async_lds16(Bb + (size_t)(r0 + 64)*512 + ko + cb, ldsB1);
    __syncthreads();   // drains vmcnt before barrier -> tiles resident

    short8 af[4], bq[4];
    #pragma unroll
    for (int i=0;i<4;i++) af[i] = *(const short8*)(As + (wv + i*16 + fr)*64 + fo);
    #pragma unroll
    for (int j=0;j<4;j++) bq[j] = *(const short8*)(Bs + (wt + j*16 + fr)*64 + fo);
    #pragma unroll
    for (int i=0;i<4;i++)
      #pragma unroll
      for (int j=0;j<4;j++)
        acc[i][j] = __builtin_amdgcn_mfma_f32_16x16x32_bf16(af[i], bq[j], acc[i][j], 0, 0, 0);
    __syncthreads();   // reads done before next stage overwrites
  }

  // epilogue: D col(lane&15)=t, row((lane>>4)*4+reg)=v
  const int tc = t0 + wt + fr;
  #pragma unroll
  for (int i=0;i<4;i++){
    int vb = v0 + wv + i*16 + (lane >> 4)*4;
    #pragma unroll
    for (int r=0;r<4;r++){
      int v = vb + r;
      float bo = b_out[v];
      float* orow = out + ((size_t)b*VOCAB + v)*TT + tc;
      #pragma unroll
      for (int j=0;j<4;j++)
        orow[j*16] = acc[i][j][r] + bo;
    }
  }
}

extern "C" void kernel_launch(void* const* d_in, const int* in_sizes, int n_in,
                              void* d_out, int out_size, void* d_ws, size_t ws_size,
                              hipStream_t stream) {
  const float* key   = (const float*)d_in[0];
  const float* value = (const float*)d_in[1];
  const int*   elen  = (const int*)  d_in[2];
  const int*   y     = (const int*)  d_in[3];
  const float* E     = (const float*)d_in[4];
  const float* W1    = (const float*)d_in[5];
  const float* bi1   = (const float*)d_in[6];
  const float* bh1   = (const float*)d_in[7];
  const float* W2    = (const float*)d_in[8];
  const float* bi2   = (const float*)d_in[9];
  const float* bh2   = (const float*)d_in[10];
  const float* bo    = (const float*)d_in[11];
  float* out = (float*)d_out;

  char* ws = (char*)d_ws;
  float*          h1  = (float*)ws;                                 // 8192*512*4  = 16,777,216
  float*          h2  = (float*)(ws + 16777216);                    // 8192*128*4  =  4,194,304
  unsigned short* Ebf = (unsigned short*)(ws + 20971520);           // 32000*256*2 = 16,384,000
  unsigned short* OC  = (unsigned short*)(ws + 37355520);           // 8192*256*2  =  4,194,304

  // 1) E -> bf16
  cvt_kernel<<<8000, 256, 0, stream>>>(E, Ebf, (VOCAB*EMBED)/4);
  // 2) layer 1: embed-gather GEMM + LSTM act -> h1 (f32)
  lstm_gemm_kernel<true, 256, 0, 1024, 1536, 512>
      <<<dim3(8, 128), 256, 0, stream>>>(E, y, W1, bi1, bh1, h1);
  // 3) layer 2 -> h2 (f32)
  lstm_gemm_kernel<false, 512, 0, 256, 384, 128>
      <<<dim3(2, 128), 256, 0, stream>>>(h1, nullptr, W2, bi2, bh2, h2);
  // 4) attention -> out_ctx bf16 (both halves)
  attn_kernel<<<512, 256, 0, stream>>>(key, value, elen, h2, OC);
  // 5) tied-weight output GEMM (bf16 MFMA) -> transposed logits
  out_gemm_kernel<<<dim3(VOCAB/128, TT/128, BB), 256, 0, stream>>>(Ebf, OC, bo, out);
}